// Round 9
// baseline (384.716 us; speedup 1.0000x reference)
//
#include <hip/hip_runtime.h>
#include <hip/hip_bf16.h>
#include <cstdint>

// ---------------- problem constants ----------------
#define BB     2
#define LSEQ   4096
#define DM     1024
#define DSSM   2048
#define NH     32
#define HD     64
#define DS     128
#define NPROJ  4384            // D_IN_PROJ
#define NPAD   4480            // padded to multiple of 128
#define CONVD  2304
#define ROWS   (BB*LSEQ)       // 8192
#define CHUNK  128
#define NCH    (LSEQ/CHUNK)    // 32
#define NBHC   (BB*NH*NCH)     // 2048

typedef __bf16 bf16x8 __attribute__((ext_vector_type(8)));
typedef __bf16 bf16x4v __attribute__((ext_vector_type(4)));
typedef float  f32x4  __attribute__((ext_vector_type(4)));
typedef float  f32x16 __attribute__((ext_vector_type(16)));

__device__ __forceinline__ __bf16 to_bf(float f) {
    __hip_bfloat16 h = __float2bfloat16(f);
    return *(__bf16*)&h;
}

// async global->LDS, 16B per lane; lds base must be wave-uniform (HW adds lane*16)
__device__ __forceinline__ void direct_load16(const void* gp, void* lp) {
    typedef const __attribute__((address_space(1))) unsigned int* gptr_t;
    typedef __attribute__((address_space(3))) unsigned int* lptr_t;
    __builtin_amdgcn_global_load_lds((gptr_t)(uintptr_t)gp,
                                     (lptr_t)(unsigned int)(uintptr_t)lp,
                                     16, 0, 0);
}

// ---------------- merged fp32 -> bf16 convert (u, W_in padded, W_out) ----------------
#define N1 ((size_t)ROWS * DM)          // u
#define N2 ((size_t)NPAD * DM)          // W_in padded
#define N3 ((size_t)DM * DSSM)          // W_out
#define NREAL ((size_t)NPROJ * DM)      // real part of W_in

__global__ __launch_bounds__(256) void convert_all(const float* __restrict__ u,
                                                   const float* __restrict__ W_in,
                                                   const float* __restrict__ W_out,
                                                   __hip_bfloat16* __restrict__ ub,
                                                   __hip_bfloat16* __restrict__ winb,
                                                   __hip_bfloat16* __restrict__ woutb) {
    size_t i4 = ((size_t)blockIdx.x * 256 + threadIdx.x) * 4;
    const float* src;
    __hip_bfloat16* dst;
    size_t j;
    if (i4 < N1) { src = u; dst = ub; j = i4; }
    else if (i4 < N1 + N2) {
        j = i4 - N1;
        if (j >= NREAL) {   // pad region (group-aligned: NREAL % 4 == 0)
            ushort4 z = {0, 0, 0, 0};
            *(ushort4*)&winb[j] = z;
            return;
        }
        src = W_in; dst = winb;
    } else { src = W_out; dst = woutb; j = i4 - N1 - N2; }
    float4 v = *(const float4*)&src[j];
    __hip_bfloat16 o[4] = {__float2bfloat16(v.x), __float2bfloat16(v.y),
                           __float2bfloat16(v.z), __float2bfloat16(v.w)};
    *(ushort4*)&dst[j] = *(ushort4*)o;
}

// ---------------- bf16 MFMA GEMM: C[M,N] = A[M,K] * B[N,K]^T ----------------
// 128x128 tile, BK=32, 32x32x16 MFMA, GROUP_M=8 swizzle, XOR-swizzled LDS
// (0 bank conflicts — round 7). Single-buffer (dbuf measured neutral, round 8).
// __launch_bounds__(256,4): force 128-reg budget -> 4 blocks/CU (was 140 regs,
// 3 blocks/CU, 28% occupancy — the ~60% latency-stall gap needs TLP).
__device__ __forceinline__ void storeC(float v, float* p) { *p = v; }
__device__ __forceinline__ void storeC(float v, __hip_bfloat16* p) { *p = __float2bfloat16(v); }

template <typename CT>
__global__ __launch_bounds__(256, 4) void gemm_bt(const __hip_bfloat16* __restrict__ A,
                                                  const __hip_bfloat16* __restrict__ B,
                                                  CT* __restrict__ C,
                                                  int M, int N, int K, int lda, int ldc) {
    __shared__ __bf16 lA[128 * 32];
    __shared__ __bf16 lB[128 * 32];
    const int tid = threadIdx.x;
    const int wv = tid >> 6, ln = tid & 63;

    // GROUP_M=8 swizzle
    const int gridM = M >> 7, gridN = N >> 7;
    const int pid = blockIdx.x;
    const int gsize = 8 * gridN;
    const int g = pid / gsize;
    const int first_m = g * 8;
    const int sz = min(8, gridM - first_m);
    const int m0 = (first_m + (pid % gsize) % sz) * 128;
    const int n0 = ((pid % gsize) / sz) * 128;

    const int wrow = (wv >> 1) * 64, wcol = (wv & 1) * 64;
    const int l31 = ln & 31, khalf = ln >> 5;
    const int sw = (l31 >> 2) & 3;           // reader-side XOR term

    f32x16 acc[2][2] = {};

    // staging: lane ln -> row16 = ln>>2, chunk = (ln&3) ^ ((ln>>4)&3)
    const int scol = (((ln & 3) ^ ((ln >> 4) & 3))) * 8;
    const int sr0 = wv * 16 + (ln >> 2);
    const int sr1 = (4 + wv) * 16 + (ln >> 2);

    const __hip_bfloat16* Ab = A + (size_t)m0 * lda;
    const __hip_bfloat16* Bb = B + (size_t)n0 * K;

    for (int k0 = 0; k0 < K; k0 += 32) {
        direct_load16(Ab + (size_t)sr0 * lda + k0 + scol, &lA[wv * 512]);
        direct_load16(Ab + (size_t)sr1 * lda + k0 + scol, &lA[(4 + wv) * 512]);
        direct_load16(Bb + (size_t)sr0 * K + k0 + scol, &lB[wv * 512]);
        direct_load16(Bb + (size_t)sr1 * K + k0 + scol, &lB[(4 + wv) * 512]);
        __syncthreads();

        #pragma unroll
        for (int ks = 0; ks < 2; ++ks) {
            const int ce = ((ks * 2 + khalf) ^ sw) * 8;   // swizzled chunk offset
            bf16x8 af[2], bfr[2];
            #pragma unroll
            for (int tm = 0; tm < 2; ++tm)
                af[tm]  = *(const bf16x8*)&lA[(wrow + tm * 32 + l31) * 32 + ce];
            #pragma unroll
            for (int tn = 0; tn < 2; ++tn)
                bfr[tn] = *(const bf16x8*)&lB[(wcol + tn * 32 + l31) * 32 + ce];
            #pragma unroll
            for (int tm = 0; tm < 2; ++tm)
                #pragma unroll
                for (int tn = 0; tn < 2; ++tn)
                    acc[tm][tn] = __builtin_amdgcn_mfma_f32_32x32x16_bf16(af[tm], bfr[tn], acc[tm][tn], 0, 0, 0);
        }
        __syncthreads();
    }

    // C/D layout (verified m74/m101): col = lane&31, row = (reg&3) + 8*(reg>>2) + 4*(lane>>5)
    #pragma unroll
    for (int tm = 0; tm < 2; ++tm) {
        #pragma unroll
        for (int tn = 0; tn < 2; ++tn) {
            const int rbase = m0 + wrow + tm * 32 + 4 * khalf;
            const int c0 = n0 + wcol + tn * 32 + l31;
            #pragma unroll
            for (int r = 0; r < 16; ++r) {
                const int row = rbase + (r & 3) + 8 * (r >> 2);
                storeC(acc[tm][tn][r], &C[(size_t)row * ldc + c0]);
            }
        }
    }
}

// ---------------- fused conv4+SiLU tile kernel ----------------
// grid (37, 128): ct<32 -> x cols (writes xT only), ct 32/33 -> B (Bv + BT),
// ct 34/35 -> C (Cv), ct 36 -> dt softplus. 64 rows x 64 cols per block.
__global__ __launch_bounds__(256) void conv_fused(const __hip_bfloat16* __restrict__ zx,
                                                  const float* __restrict__ conv_w,
                                                  const float* __restrict__ conv_b,
                                                  const float* __restrict__ dt_bias,
                                                  __hip_bfloat16* __restrict__ xT,
                                                  __hip_bfloat16* __restrict__ Bv,
                                                  __hip_bfloat16* __restrict__ Cv,
                                                  __hip_bfloat16* __restrict__ BT,
                                                  float* __restrict__ dtv) {
    const int ct = blockIdx.x;
    const int rb = blockIdx.y * 64;
    const int tid = threadIdx.x;
    const int b = rb >> 12, l0 = rb & (LSEQ - 1);

    if (ct == 36) {   // dt: 64 rows x 32 heads
        const int r = tid >> 2, h8 = (tid & 3) * 8;
        const int gr = rb + r;
        bf16x8 v8 = *(const bf16x8*)&zx[(size_t)gr * NPAD + DSSM + CONVD + h8];
        float o[8];
        #pragma unroll
        for (int j = 0; j < 8; ++j) {
            float v = (float)v8[j] + dt_bias[h8 + j];
            o[j] = (v > 20.f) ? v : log1pf(__expf(v));
        }
        *(float4*)&dtv[(size_t)gr * NH + h8]     = *(float4*)&o[0];
        *(float4*)&dtv[(size_t)gr * NH + h8 + 4] = *(float4*)&o[4];
        return;
    }

    __shared__ __bf16 t[64][72];
    const int c0 = ct * 64;
    const int sc = (tid & 7) * 8;       // local col group (8 cols)
    const int r2 = (tid >> 3) * 2;      // local row base (2 rows per thread)
    const int gc = c0 + sc;

    float cb[8];
    *(float4*)&cb[0] = *(const float4*)&conv_b[gc];
    *(float4*)&cb[4] = *(const float4*)&conv_b[gc + 4];
    float4 cw[8];
    #pragma unroll
    for (int j = 0; j < 8; ++j) cw[j] = *(const float4*)&conv_w[(gc + j) * 4];

    float in[5][8];
    #pragma unroll
    for (int i = 0; i < 5; ++i) {
        int ll = l0 + r2 - 3 + i;
        if (ll >= 0) {
            bf16x8 v = *(const bf16x8*)&zx[(size_t)(b * LSEQ + ll) * NPAD + DSSM + gc];
            #pragma unroll
            for (int j = 0; j < 8; ++j) in[i][j] = (float)v[j];
        } else {
            #pragma unroll
            for (int j = 0; j < 8; ++j) in[i][j] = 0.f;
        }
    }

    bf16x8 o0, o1;
    #pragma unroll
    for (int j = 0; j < 8; ++j) {
        float a0 = cb[j] + cw[j].x * in[0][j] + cw[j].y * in[1][j] + cw[j].z * in[2][j] + cw[j].w * in[3][j];
        float a1 = cb[j] + cw[j].x * in[1][j] + cw[j].y * in[2][j] + cw[j].z * in[3][j] + cw[j].w * in[4][j];
        o0[j] = to_bf(a0 / (1.f + __expf(-a0)));
        o1[j] = to_bf(a1 / (1.f + __expf(-a1)));
    }

    // row-major writes for B/C
    if (ct >= 32 && ct < 34) {
        const int bc = gc - 2048;
        *(bf16x8*)&Bv[(size_t)(rb + r2) * DS + bc]     = o0;
        *(bf16x8*)&Bv[(size_t)(rb + r2 + 1) * DS + bc] = o1;
    } else if (ct >= 34) {
        const int cc = gc - 2176;
        *(bf16x8*)&Cv[(size_t)(rb + r2) * DS + cc]     = o0;
        *(bf16x8*)&Cv[(size_t)(rb + r2 + 1) * DS + cc] = o1;
    }

    // LDS-transpose for xT (ct<32) and BT (ct 32/33)
    if (ct < 34) {
        #pragma unroll
        for (int j = 0; j < 8; ++j) { t[sc + j][r2] = o0[j]; t[sc + j][r2 + 1] = o1[j]; }
        __syncthreads();
        const int trow = tid >> 3, tcolg = (tid & 7) * 8;
        #pragma unroll
        for (int hfl = 0; hfl < 2; ++hfl) {
            const int rr = hfl * 32 + trow;   // local col index
            bf16x8 o;
            #pragma unroll
            for (int j = 0; j < 8; ++j) o[j] = t[rr][tcolg + j];
            __hip_bfloat16* dst = (ct < 32)
                ? &xT[(size_t)(b * DSSM + c0 + rr) * LSEQ + l0 + tcolg]
                : &BT[(size_t)(b * DS + (c0 - 2048) + rr) * LSEQ + l0 + tcolg];
            *(bf16x8*)dst = o;
        }
    }
}

// ---------------- Phase A: per-chunk local state Sloc + decay cumsum ----------------
__global__ __launch_bounds__(256) void chunk_local(const __hip_bfloat16* __restrict__ xT,
                                                   const __hip_bfloat16* __restrict__ BT,
                                                   const float* __restrict__ dtv,
                                                   const float* __restrict__ A_log,
                                                   __hip_bfloat16* __restrict__ sst,
                                                   float* __restrict__ lcg) {
    __shared__ __bf16 lXT[4][HD * 32];   // [k-slice][p*32 + s']
    __shared__ __bf16 lBT[4][DS * 32];   // [k-slice][n*32 + s']
    __shared__ float sc[2][CHUNK];
    __shared__ float lw[CHUNK];

    const int bid = blockIdx.x;
    const int c = bid & 31, hh = (bid >> 5) & 31, b = bid >> 10;
    const int tid = threadIdx.x;
    const int wv = tid >> 6, ln = tid & 63;
    const int r0 = b * LSEQ + c * CHUNK;
    const int s0 = c * CHUNK;

    // async-stage B^T
    {
        const int row16 = ln >> 2, col8 = (ln & 3) * 8;
        const __hip_bfloat16* Bb = BT + (size_t)b * DS * LSEQ + s0 + wv * 32 + col8;
        #pragma unroll
        for (int j = 0; j < 8; ++j)
            direct_load16(Bb + (size_t)(j * 16 + row16) * LSEQ, &lBT[wv][j * 512]);
    }

    // inclusive cumsum of la_s = A*dt_s (Hillis-Steele)
    float dt_s = 0.f;
    if (tid < CHUNK) {
        dt_s = dtv[(size_t)(r0 + tid) * NH + hh];
        sc[0][tid] = -__expf(A_log[hh]) * dt_s;
    }
    __syncthreads();
    int src = 0;
    for (int off = 1; off < CHUNK; off <<= 1) {
        if (tid < CHUNK)
            sc[src ^ 1][tid] = sc[src][tid] + ((tid >= off) ? sc[src][tid - off] : 0.f);
        __syncthreads();
        src ^= 1;
    }
    if (tid < CHUNK) {
        float Lc = sc[src][tid];
        lcg[(size_t)bid * CHUNK + tid] = Lc;
        lw[tid] = dt_s * __expf(sc[src][CHUNK - 1] - Lc);
    }
    __syncthreads();

    // stage weighted X^T
    {
        const int p = tid >> 2, ks = tid & 3;
        const __hip_bfloat16* xr = xT + (size_t)(b * DSSM + hh * HD + p) * LSEQ + s0 + ks * 32;
        #pragma unroll
        for (int v = 0; v < 4; ++v) {
            bf16x8 xv = *(const bf16x8*)&xr[v * 8];
            float4 w0 = *(const float4*)&lw[ks * 32 + v * 8];
            float4 w1 = *(const float4*)&lw[ks * 32 + v * 8 + 4];
            bf16x8 o;
            o[0] = to_bf((float)xv[0] * w0.x); o[1] = to_bf((float)xv[1] * w0.y);
            o[2] = to_bf((float)xv[2] * w0.z); o[3] = to_bf((float)xv[3] * w0.w);
            o[4] = to_bf((float)xv[4] * w1.x); o[5] = to_bf((float)xv[5] * w1.y);
            o[6] = to_bf((float)xv[6] * w1.z); o[7] = to_bf((float)xv[7] * w1.w);
            *(bf16x8*)&lXT[ks][p * 32 + v * 8] = o;
        }
    }
    __syncthreads();

    const int lane15 = ln & 15, quad = ln >> 4;
    f32x4 acc[4][2] = {};
    #pragma unroll
    for (int ks = 0; ks < 4; ++ks) {
        bf16x8 af[4], bf[2];
        #pragma unroll
        for (int mi = 0; mi < 4; ++mi)
            af[mi] = *(const bf16x8*)&lXT[ks][(mi * 16 + lane15) * 32 + quad * 8];
        #pragma unroll
        for (int ni = 0; ni < 2; ++ni)
            bf[ni] = *(const bf16x8*)&lBT[ks][(wv * 32 + ni * 16 + lane15) * 32 + quad * 8];
        #pragma unroll
        for (int mi = 0; mi < 4; ++mi)
            #pragma unroll
            for (int ni = 0; ni < 2; ++ni)
                acc[mi][ni] = __builtin_amdgcn_mfma_f32_16x16x32_bf16(af[mi], bf[ni], acc[mi][ni], 0, 0, 0);
    }

    __hip_bfloat16* sb = sst + (size_t)bid * (HD * DS);
    #pragma unroll
    for (int mi = 0; mi < 4; ++mi)
        #pragma unroll
        for (int ni = 0; ni < 2; ++ni) {
            int p0 = mi * 16 + quad * 4;
            int n0 = wv * 32 + ni * 16 + lane15;
            #pragma unroll
            for (int r = 0; r < 4; ++r)
                sb[(size_t)(p0 + r) * DS + n0] = __float2bfloat16(acc[mi][ni][r]);
        }
}

// ---------------- Phase B: inter-chunk prefix (in-place Sloc -> h_init) ----------------
// All 32 chunk loads are independent: batch them into registers (one latency
// exposure), run the recurrence in regs, store all back (was 32 serial
// dependent global round-trips).
__global__ __launch_bounds__(256) void chunk_scan(__hip_bfloat16* __restrict__ sst,
                                                  const float* __restrict__ lcg) {
    const int bid = blockIdx.x;               // 2048
    const int bh = bid >> 5;
    const int elem = (bid & 31) * 256 + threadIdx.x;
    size_t base = (size_t)bh * NCH * (HD * DS) + elem;
    const float* lg = lcg + (size_t)bh * NCH * CHUNK;

    float v[NCH];
    #pragma unroll
    for (int cc = 0; cc < NCH; ++cc)
        v[cc] = __bfloat162float(sst[base + (size_t)cc * (HD * DS)]);

    float h = 0.f;
    #pragma unroll
    for (int cc = 0; cc < NCH; ++cc) {
        float cq = __expf(lg[cc * CHUNK + CHUNK - 1]);
        float sv = v[cc];
        v[cc] = h;
        h = cq * h + sv;
    }

    #pragma unroll
    for (int cc = 0; cc < NCH; ++cc)
        sst[base + (size_t)cc * (HD * DS)] = __float2bfloat16(v[cc]);
}

// ---------------- Phase C: Y = (mask(C B^T)*dt) @ X + diag(cum) C @ h^T + D*x ----------------
// Gt = B @ C^T orientation: s in regs, t in lanes -> S written as b64 (4 consecutive s).
__global__ __launch_bounds__(256) void chunk_y(const __hip_bfloat16* __restrict__ xT,
                                               const __hip_bfloat16* __restrict__ Bv,
                                               const __hip_bfloat16* __restrict__ Cv,
                                               const float* __restrict__ dtv,
                                               const float* __restrict__ lcg,
                                               const __hip_bfloat16* __restrict__ sst,
                                               const float* __restrict__ Dv,
                                               __hip_bfloat16* __restrict__ y) {
    __shared__ __bf16 lC[4][128 * 32];   // C slices over n; later S slices over s
    __shared__ __bf16 lB[4][128 * 32];   // B slices over n; later X^T slices over s
    __shared__ float sLc[CHUNK];
    __shared__ float sdt[CHUNK];

    const int bid = blockIdx.x;
    const int c = bid & 31, hh = (bid >> 5) & 31, b = bid >> 10;
    const int tid = threadIdx.x;
    const int wv = tid >> 6, ln = tid & 63;
    const int lane15 = ln & 15, quad = ln >> 4;
    const int r0 = b * LSEQ + c * CHUNK;

    const __hip_bfloat16* Cb = Cv + (size_t)r0 * DS;
    const __hip_bfloat16* Bb = Bv + (size_t)r0 * DS;
    const __hip_bfloat16* Hb = sst + (size_t)bid * (HD * DS);

    {
        const int i3 = ln & 3, i4 = ln >> 2;
        #pragma unroll
        for (int j = 0; j < 8; ++j) {
            direct_load16(Cb + (size_t)(j * 16 + i4) * DS + wv * 32 + i3 * 8, &lC[wv][j * 512]);
            direct_load16(Bb + (size_t)(j * 16 + i4) * DS + wv * 32 + i3 * 8, &lB[wv][j * 512]);
        }
    }
    if (tid < CHUNK) {
        sLc[tid] = lcg[(size_t)bid * CHUNK + tid];
        sdt[tid] = dtv[(size_t)(r0 + tid) * NH + hh];
    }
    __syncthreads();

    const int wrow = (wv >> 1) * 64, wcol = (wv & 1) * 64;  // Gt quadrant (s rows, t cols)
    const int wr2 = wv * 32;                                 // Y rows
    f32x4 acc[4][4] = {};
    f32x4 accY[2][4] = {};

    // Gt = B @ C^T (K=n) and Y2 = C @ h^T (K=n, h B-frags direct from global)
    #pragma unroll
    for (int ks = 0; ks < 4; ++ks) {
        bf16x8 af[4], bfr[4], af2[2], bh[4];
        #pragma unroll
        for (int i = 0; i < 4; ++i) {
            af[i]  = *(const bf16x8*)&lB[ks][(wrow + i * 16 + lane15) * 32 + quad * 8];   // B rows s
            bfr[i] = *(const bf16x8*)&lC[ks][(wcol + i * 16 + lane15) * 32 + quad * 8];   // C rows t
        }
        #pragma unroll
        for (int mi = 0; mi < 2; ++mi)
            af2[mi] = *(const bf16x8*)&lC[ks][(wr2 + mi * 16 + lane15) * 32 + quad * 8];
        #pragma unroll
        for (int ni = 0; ni < 4; ++ni)
            bh[ni] = *(const bf16x8*)&Hb[(size_t)(ni * 16 + lane15) * DS + ks * 32 + quad * 8];
        #pragma unroll
        for (int mi = 0; mi < 4; ++mi)
            #pragma unroll
            for (int ni = 0; ni < 4; ++ni)
                acc[mi][ni] = __builtin_amdgcn_mfma_f32_16x16x32_bf16(af[mi], bfr[ni], acc[mi][ni], 0, 0, 0);
        #pragma unroll
        for (int mi = 0; mi < 2; ++mi)
            #pragma unroll
            for (int ni = 0; ni < 4; ++ni)
                accY[mi][ni] = __builtin_amdgcn_mfma_f32_16x16x32_bf16(af2[mi], bh[ni], accY[mi][ni], 0, 0, 0);
    }

    // scale Y2 rows by cum_t = exp(Lc_t)
    #pragma unroll
    for (int mi = 0; mi < 2; ++mi)
        #pragma unroll
        for (int r = 0; r < 4; ++r) {
            float cum = __expf(sLc[wr2 + mi * 16 + quad * 4 + r]);
            #pragma unroll
            for (int ni = 0; ni < 4; ++ni) accY[mi][ni][r] *= cum;
        }

    __syncthreads();   // all Gt/Y2 LDS reads done

    // async-stage X^T from xT into lB (overlaps with S-mask VALU below)
    {
        const int row16 = ln >> 2, col8 = (ln & 3) * 8;
        const __hip_bfloat16* xr = xT + (size_t)(b * DSSM + hh * HD) * LSEQ + c * CHUNK + wv * 32 + col8;
        #pragma unroll
        for (int j = 0; j < 4; ++j)
            direct_load16(xr + (size_t)(j * 16 + row16) * LSEQ, &lB[wv][j * 512]);
    }

    // mask+decay Gt -> S[t][s], b64 writes (4 consecutive s per reg group)
    #pragma unroll
    for (int mi = 0; mi < 4; ++mi) {
        const int sb = wrow + mi * 16 + quad * 4;
        float el[4], dt4[4];
        #pragma unroll
        for (int r = 0; r < 4; ++r) { el[r] = sLc[sb + r]; dt4[r] = sdt[sb + r]; }
        #pragma unroll
        for (int ni = 0; ni < 4; ++ni) {
            const int t = wcol + ni * 16 + lane15;
            const float Lct = sLc[t];
            bf16x4v o;
            #pragma unroll
            for (int r = 0; r < 4; ++r) {
                const int s = sb + r;
                float v = (s <= t) ? acc[mi][ni][r] * __expf(Lct - el[r]) * dt4[r] : 0.f;
                o[r] = to_bf(v);
            }
            *(bf16x4v*)&lC[sb >> 5][t * 32 + (sb & 31)] = o;
        }
    }
    __syncthreads();

    // Y1 = S @ X (K=s)
    #pragma unroll
    for (int ks = 0; ks < 4; ++ks) {
        bf16x8 af2[2], bx[4];
        #pragma unroll
        for (int mi = 0; mi < 2; ++mi)
            af2[mi] = *(const bf16x8*)&lC[ks][(wr2 + mi * 16 + lane15) * 32 + quad * 8];
        #pragma unroll
        for (int ni = 0; ni < 4; ++ni)
            bx[ni] = *(const bf16x8*)&lB[ks][(ni * 16 + lane15) * 32 + quad * 8];
        #pragma unroll
        for (int mi = 0; mi < 2; ++mi)
            #pragma unroll
            for (int ni = 0; ni < 4; ++ni)
                accY[mi][ni] = __builtin_amdgcn_mfma_f32_16x16x32_bf16(af2[mi], bx[ni], accY[mi][ni], 0, 0, 0);
    }

    // + D * x  (x[t][p] still in lB)
    const float dsc = Dv[hh];
    #pragma unroll
    for (int mi = 0; mi < 2; ++mi)
        #pragma unroll
        for (int ni = 0; ni < 4; ++ni) {
            const int p0 = ni * 16 + lane15;
            #pragma unroll
            for (int r = 0; r < 4; ++r) {
                const int t = wr2 + mi * 16 + quad * 4 + r;
                accY[mi][ni][r] += dsc * (float)lB[t >> 5][p0 * 32 + (t & 31)];
            }
        }

    // epilogue
    __hip_bfloat16* yb = y + (size_t)r0 * DSSM + hh * HD;
    #pragma unroll
    for (int mi = 0; mi < 2; ++mi)
        #pragma unroll
        for (int ni = 0; ni < 4; ++ni) {
            const int p0 = ni * 16 + lane15;
            #pragma unroll
            for (int r = 0; r < 4; ++r) {
                const int t = wr2 + mi * 16 + quad * 4 + r;
                yb[(size_t)t * DSSM + p0] = __float2bfloat16(accY[mi][ni][r]);
            }
        }
}

// ---------------- y(+Dx already), gate, RMSNorm -> g (into zx cols [2048,4096)) ----------------
__global__ __launch_bounds__(256) void gnorm_kernel(const __hip_bfloat16* __restrict__ y,
                                                    __hip_bfloat16* __restrict__ zx,
                                                    const float* __restrict__ nw) {
    const int r = blockIdx.x;
    const int tid = threadIdx.x;
    const int c = tid * 8;
    const size_t off = (size_t)r * DSSM + c;
    bf16x8 yv8 = *(const bf16x8*)&y[off];
    bf16x8 zv8 = *(const bf16x8*)&zx[(size_t)r * NPAD + c];
    float gv[8];
    float ss = 0.f;
    #pragma unroll
    for (int i = 0; i < 8; ++i) {
        float yv = (float)yv8[i];
        float z = (float)zv8[i];
        float gq = yv * (z / (1.f + __expf(-z)));
        gv[i] = gq;
        ss += gq * gq;
    }
    #pragma unroll
    for (int o = 32; o; o >>= 1) ss += __shfl_xor(ss, o, 64);
    __shared__ float ws4[4];
    if ((tid & 63) == 0) ws4[tid >> 6] = ss;
    __syncthreads();
    const float tot = ws4[0] + ws4[1] + ws4[2] + ws4[3];
    const float scale = rsqrtf(tot * (1.f / (float)DSSM) + 1e-5f);
    bf16x8 o;
    #pragma unroll
    for (int i = 0; i < 8; ++i) o[i] = to_bf(gv[i] * scale * nw[c + i]);
    *(bf16x8*)&zx[(size_t)r * NPAD + DSSM + c] = o;
}

// ---------------- launch ----------------
extern "C" void kernel_launch(void* const* d_in, const int* in_sizes, int n_in,
                              void* d_out, int out_size, void* d_ws, size_t ws_size,
                              hipStream_t stream) {
    const float* u       = (const float*)d_in[0];
    const float* W_in    = (const float*)d_in[1];
    const float* conv_w  = (const float*)d_in[2];
    const float* conv_b  = (const float*)d_in[3];
    const float* dt_bias = (const float*)d_in[4];
    const float* A_log   = (const float*)d_in[5];
    const float* Dv      = (const float*)d_in[6];
    const float* norm_w  = (const float*)d_in[7];
    const float* W_out   = (const float*)d_in[8];
    float* out = (float*)d_out;

    char* ws = (char*)d_ws;
    size_t off = 0;
    auto alloc = [&](size_t bytes) { char* p = ws + off; off += (bytes + 255) & ~(size_t)255; return p; };

    // ~210 MB total
    __hip_bfloat16* ub    = (__hip_bfloat16*)alloc((size_t)ROWS * DM * 2);       // 16.8 MB
    __hip_bfloat16* winb  = (__hip_bfloat16*)alloc((size_t)NPAD * DM * 2);       //  9.2 MB
    __hip_bfloat16* woutb = (__hip_bfloat16*)alloc((size_t)DM * DSSM * 2);       //  4.2 MB
    __hip_bfloat16* zx    = (__hip_bfloat16*)alloc((size_t)ROWS * NPAD * 2);     // 73.4 MB
    __hip_bfloat16* yb    = (__hip_bfloat16*)alloc((size_t)ROWS * DSSM * 2);     // 33.6 MB
    __hip_bfloat16* sst   = (__hip_bfloat16*)alloc((size_t)NBHC * HD * DS * 2);  // 33.6 MB
    __hip_bfloat16* xT    = (__hip_bfloat16*)alloc((size_t)ROWS * DSSM * 2);     // 33.6 MB
    __hip_bfloat16* BT    = (__hip_bfloat16*)alloc((size_t)ROWS * DS * 2);       //  2.1 MB

    // ub dead after GEMM1 -> B/C (bf16) + dt (fp32)
    __hip_bfloat16* Bvp = (__hip_bfloat16*)ub;
    __hip_bfloat16* Cvp = Bvp + (size_t)ROWS * DS;
    float*          dtv = (float*)(Cvp + (size_t)ROWS * DS);
    // winb dead after GEMM1 -> Lc cumsums
    float*          lcg = (float*)winb;

    // merged converts
    convert_all<<<(unsigned)((N1 + N2 + N3) / 4 / 256), 256, 0, stream>>>(
        u, W_in, W_out, ub, winb, woutb);

    // GEMM1: zx[8192, 4480](bf16) = u @ W_in^T (padded), 1D swizzled grid
    gemm_bt<__hip_bfloat16><<<(ROWS / 128) * (NPAD / 128), 256, 0, stream>>>(
        ub, winb, zx, ROWS, NPAD, DM, DM, NPAD);

    // fused conv + silu + dt + transposes (overwrites ub-region with B/C/dt)
    conv_fused<<<dim3(37, ROWS / 64), 256, 0, stream>>>(
        zx, conv_w, conv_b, dt_bias, xT, Bvp, Cvp, BT, dtv);

    // chunked scan: local states -> prefix -> Y
    chunk_local<<<NBHC, 256, 0, stream>>>(xT, BT, dtv, A_log, sst, lcg);
    chunk_scan<<<NBHC, 256, 0, stream>>>(sst, lcg);
    chunk_y<<<NBHC, 256, 0, stream>>>(xT, Bvp, Cvp, dtv, lcg, sst, Dv, yb);

    // gate + norm; writes g into zx cols [2048, 4096)
    gnorm_kernel<<<ROWS, 256, 0, stream>>>(yb, zx, norm_w);

    // GEMM2: out[8192,1024](fp32) = g @ W_out^T   (g lives in zx, lda = NPAD)
    gemm_bt<float><<<(ROWS / 128) * (DM / 128), 256, 0, stream>>>(
        zx + DSSM, woutb, out, ROWS, DM, DSSM, NPAD, DM);
}

// Round 10
// 362.000 us; speedup vs baseline: 1.0628x; 1.0628x over previous
//
#include <hip/hip_runtime.h>
#include <hip/hip_bf16.h>
#include <cstdint>

// ---------------- problem constants ----------------
#define BB     2
#define LSEQ   4096
#define DM     1024
#define DSSM   2048
#define NH     32
#define HD     64
#define DS     128
#define NPROJ  4384            // D_IN_PROJ
#define NPAD   4480            // padded to multiple of 128
#define CONVD  2304
#define ROWS   (BB*LSEQ)       // 8192
#define CHUNK  128
#define NCH    (LSEQ/CHUNK)    // 32
#define NBHC   (BB*NH*NCH)     // 2048

typedef __bf16 bf16x8 __attribute__((ext_vector_type(8)));
typedef __bf16 bf16x4v __attribute__((ext_vector_type(4)));
typedef float  f32x4  __attribute__((ext_vector_type(4)));
typedef float  f32x16 __attribute__((ext_vector_type(16)));

__device__ __forceinline__ __bf16 to_bf(float f) {
    __hip_bfloat16 h = __float2bfloat16(f);
    return *(__bf16*)&h;
}

// async global->LDS, 16B per lane; lds base must be wave-uniform (HW adds lane*16)
__device__ __forceinline__ void direct_load16(const void* gp, void* lp) {
    typedef const __attribute__((address_space(1))) unsigned int* gptr_t;
    typedef __attribute__((address_space(3))) unsigned int* lptr_t;
    __builtin_amdgcn_global_load_lds((gptr_t)(uintptr_t)gp,
                                     (lptr_t)(unsigned int)(uintptr_t)lp,
                                     16, 0, 0);
}

// ---------------- merged fp32 -> bf16 convert (u, W_in padded, W_out) ----------------
#define N1 ((size_t)ROWS * DM)          // u
#define N2 ((size_t)NPAD * DM)          // W_in padded
#define N3 ((size_t)DM * DSSM)          // W_out
#define NREAL ((size_t)NPROJ * DM)      // real part of W_in

__global__ __launch_bounds__(256) void convert_all(const float* __restrict__ u,
                                                   const float* __restrict__ W_in,
                                                   const float* __restrict__ W_out,
                                                   __hip_bfloat16* __restrict__ ub,
                                                   __hip_bfloat16* __restrict__ winb,
                                                   __hip_bfloat16* __restrict__ woutb) {
    size_t i4 = ((size_t)blockIdx.x * 256 + threadIdx.x) * 4;
    const float* src;
    __hip_bfloat16* dst;
    size_t j;
    if (i4 < N1) { src = u; dst = ub; j = i4; }
    else if (i4 < N1 + N2) {
        j = i4 - N1;
        if (j >= NREAL) {   // pad region (group-aligned: NREAL % 4 == 0)
            ushort4 z = {0, 0, 0, 0};
            *(ushort4*)&winb[j] = z;
            return;
        }
        src = W_in; dst = winb;
    } else { src = W_out; dst = woutb; j = i4 - N1 - N2; }
    float4 v = *(const float4*)&src[j];
    __hip_bfloat16 o[4] = {__float2bfloat16(v.x), __float2bfloat16(v.y),
                           __float2bfloat16(v.z), __float2bfloat16(v.w)};
    *(ushort4*)&dst[j] = *(ushort4*)o;
}

// ---------------- bf16 MFMA GEMM: C[M,N] = A[M,K] * B[N,K]^T ----------------
// 128x128 tile, BK=64, 32x32x16 MFMA, GROUP_M=8 swizzle, XOR-swizzled LDS:
// chunk kc of row r lives at r*64 + (kc^(r&7))*8 -> fragment reads spread over
// all 8 bank-quads (4 lanes each), conflict-free. 16 MFMA per barrier (2x the
// BK=32 version — barrier drain was the residual stall at 101 us, round 7).
// Plain launch_bounds: the (256,4) reg-squeeze regressed 101->110 (round 9).
__device__ __forceinline__ void storeC(float v, float* p) { *p = v; }
__device__ __forceinline__ void storeC(float v, __hip_bfloat16* p) { *p = __float2bfloat16(v); }

template <typename CT>
__global__ __launch_bounds__(256) void gemm_bt(const __hip_bfloat16* __restrict__ A,
                                               const __hip_bfloat16* __restrict__ B,
                                               CT* __restrict__ C,
                                               int M, int N, int K, int lda, int ldc) {
    __shared__ __bf16 lA[128 * 64];
    __shared__ __bf16 lB[128 * 64];
    const int tid = threadIdx.x;
    const int wv = tid >> 6, ln = tid & 63;

    // GROUP_M=8 swizzle
    const int gridM = M >> 7, gridN = N >> 7;
    const int pid = blockIdx.x;
    const int gsize = 8 * gridN;
    const int g = pid / gsize;
    const int first_m = g * 8;
    const int sz = min(8, gridM - first_m);
    const int m0 = (first_m + (pid % gsize) % sz) * 128;
    const int n0 = ((pid % gsize) / sz) * 128;

    const int wrow = (wv >> 1) * 64, wcol = (wv & 1) * 64;
    const int l31 = ln & 31, khalf = ln >> 5;
    const int swr = l31 & 7;                 // reader-side XOR term (row&7)

    f32x16 acc[2][2] = {};

    // staging: wave wv covers rows [wv*32, wv*32+32), 4 issues x 8 rows.
    // lane ln -> row +ln>>3, stored chunk ln&7, global chunk (ln&7)^((ln>>3)&7)
    const int srow = ln >> 3;
    const int scol = ((ln & 7) ^ (srow & 7)) * 8;

    const __hip_bfloat16* Ab = A + (size_t)(m0 + wv * 32) * lda;
    const __hip_bfloat16* Bb = B + (size_t)(n0 + wv * 32) * K;

    for (int k0 = 0; k0 < K; k0 += 64) {
        #pragma unroll
        for (int j = 0; j < 4; ++j)
            direct_load16(Ab + (size_t)(j * 8 + srow) * lda + k0 + scol,
                          &lA[(wv * 32 + j * 8) * 64]);
        #pragma unroll
        for (int j = 0; j < 4; ++j)
            direct_load16(Bb + (size_t)(j * 8 + srow) * K + k0 + scol,
                          &lB[(wv * 32 + j * 8) * 64]);
        __syncthreads();

        #pragma unroll
        for (int kk = 0; kk < 4; ++kk) {
            const int ce = ((kk * 2 + khalf) ^ swr) * 8;   // swizzled chunk offset
            bf16x8 af[2], bfr[2];
            #pragma unroll
            for (int tm = 0; tm < 2; ++tm)
                af[tm]  = *(const bf16x8*)&lA[(wrow + tm * 32 + l31) * 64 + ce];
            #pragma unroll
            for (int tn = 0; tn < 2; ++tn)
                bfr[tn] = *(const bf16x8*)&lB[(wcol + tn * 32 + l31) * 64 + ce];
            #pragma unroll
            for (int tm = 0; tm < 2; ++tm)
                #pragma unroll
                for (int tn = 0; tn < 2; ++tn)
                    acc[tm][tn] = __builtin_amdgcn_mfma_f32_32x32x16_bf16(af[tm], bfr[tn], acc[tm][tn], 0, 0, 0);
        }
        __syncthreads();
    }

    // C/D layout (verified m74/m101): col = lane&31, row = (reg&3) + 8*(reg>>2) + 4*(lane>>5)
    #pragma unroll
    for (int tm = 0; tm < 2; ++tm) {
        #pragma unroll
        for (int tn = 0; tn < 2; ++tn) {
            const int rbase = m0 + wrow + tm * 32 + 4 * khalf;
            const int c0 = n0 + wcol + tn * 32 + l31;
            #pragma unroll
            for (int r = 0; r < 16; ++r) {
                const int row = rbase + (r & 3) + 8 * (r >> 2);
                storeC(acc[tm][tn][r], &C[(size_t)row * ldc + c0]);
            }
        }
    }
}

// ---------------- fused conv4+SiLU tile kernel ----------------
// grid (37, 128): ct<32 -> x cols (writes xT only), ct 32/33 -> B (Bv + BT),
// ct 34/35 -> C (Cv), ct 36 -> dt softplus. 64 rows x 64 cols per block.
__global__ __launch_bounds__(256) void conv_fused(const __hip_bfloat16* __restrict__ zx,
                                                  const float* __restrict__ conv_w,
                                                  const float* __restrict__ conv_b,
                                                  const float* __restrict__ dt_bias,
                                                  __hip_bfloat16* __restrict__ xT,
                                                  __hip_bfloat16* __restrict__ Bv,
                                                  __hip_bfloat16* __restrict__ Cv,
                                                  __hip_bfloat16* __restrict__ BT,
                                                  float* __restrict__ dtv) {
    const int ct = blockIdx.x;
    const int rb = blockIdx.y * 64;
    const int tid = threadIdx.x;
    const int b = rb >> 12, l0 = rb & (LSEQ - 1);

    if (ct == 36) {   // dt: 64 rows x 32 heads
        const int r = tid >> 2, h8 = (tid & 3) * 8;
        const int gr = rb + r;
        bf16x8 v8 = *(const bf16x8*)&zx[(size_t)gr * NPAD + DSSM + CONVD + h8];
        float o[8];
        #pragma unroll
        for (int j = 0; j < 8; ++j) {
            float v = (float)v8[j] + dt_bias[h8 + j];
            o[j] = (v > 20.f) ? v : log1pf(__expf(v));
        }
        *(float4*)&dtv[(size_t)gr * NH + h8]     = *(float4*)&o[0];
        *(float4*)&dtv[(size_t)gr * NH + h8 + 4] = *(float4*)&o[4];
        return;
    }

    __shared__ __bf16 t[64][72];
    const int c0 = ct * 64;
    const int sc = (tid & 7) * 8;       // local col group (8 cols)
    const int r2 = (tid >> 3) * 2;      // local row base (2 rows per thread)
    const int gc = c0 + sc;

    float cb[8];
    *(float4*)&cb[0] = *(const float4*)&conv_b[gc];
    *(float4*)&cb[4] = *(const float4*)&conv_b[gc + 4];
    float4 cw[8];
    #pragma unroll
    for (int j = 0; j < 8; ++j) cw[j] = *(const float4*)&conv_w[(gc + j) * 4];

    float in[5][8];
    #pragma unroll
    for (int i = 0; i < 5; ++i) {
        int ll = l0 + r2 - 3 + i;
        if (ll >= 0) {
            bf16x8 v = *(const bf16x8*)&zx[(size_t)(b * LSEQ + ll) * NPAD + DSSM + gc];
            #pragma unroll
            for (int j = 0; j < 8; ++j) in[i][j] = (float)v[j];
        } else {
            #pragma unroll
            for (int j = 0; j < 8; ++j) in[i][j] = 0.f;
        }
    }

    bf16x8 o0, o1;
    #pragma unroll
    for (int j = 0; j < 8; ++j) {
        float a0 = cb[j] + cw[j].x * in[0][j] + cw[j].y * in[1][j] + cw[j].z * in[2][j] + cw[j].w * in[3][j];
        float a1 = cb[j] + cw[j].x * in[1][j] + cw[j].y * in[2][j] + cw[j].z * in[3][j] + cw[j].w * in[4][j];
        o0[j] = to_bf(a0 / (1.f + __expf(-a0)));
        o1[j] = to_bf(a1 / (1.f + __expf(-a1)));
    }

    // row-major writes for B/C
    if (ct >= 32 && ct < 34) {
        const int bc = gc - 2048;
        *(bf16x8*)&Bv[(size_t)(rb + r2) * DS + bc]     = o0;
        *(bf16x8*)&Bv[(size_t)(rb + r2 + 1) * DS + bc] = o1;
    } else if (ct >= 34) {
        const int cc = gc - 2176;
        *(bf16x8*)&Cv[(size_t)(rb + r2) * DS + cc]     = o0;
        *(bf16x8*)&Cv[(size_t)(rb + r2 + 1) * DS + cc] = o1;
    }

    // LDS-transpose for xT (ct<32) and BT (ct 32/33)
    if (ct < 34) {
        #pragma unroll
        for (int j = 0; j < 8; ++j) { t[sc + j][r2] = o0[j]; t[sc + j][r2 + 1] = o1[j]; }
        __syncthreads();
        const int trow = tid >> 3, tcolg = (tid & 7) * 8;
        #pragma unroll
        for (int hfl = 0; hfl < 2; ++hfl) {
            const int rr = hfl * 32 + trow;   // local col index
            bf16x8 o;
            #pragma unroll
            for (int j = 0; j < 8; ++j) o[j] = t[rr][tcolg + j];
            __hip_bfloat16* dst = (ct < 32)
                ? &xT[(size_t)(b * DSSM + c0 + rr) * LSEQ + l0 + tcolg]
                : &BT[(size_t)(b * DS + (c0 - 2048) + rr) * LSEQ + l0 + tcolg];
            *(bf16x8*)dst = o;
        }
    }
}

// ---------------- Phase A: per-chunk local state Sloc + decay cumsum ----------------
__global__ __launch_bounds__(256) void chunk_local(const __hip_bfloat16* __restrict__ xT,
                                                   const __hip_bfloat16* __restrict__ BT,
                                                   const float* __restrict__ dtv,
                                                   const float* __restrict__ A_log,
                                                   __hip_bfloat16* __restrict__ sst,
                                                   float* __restrict__ lcg) {
    __shared__ __bf16 lXT[4][HD * 32];   // [k-slice][p*32 + s']
    __shared__ __bf16 lBT[4][DS * 32];   // [k-slice][n*32 + s']
    __shared__ float sc[2][CHUNK];
    __shared__ float lw[CHUNK];

    const int bid = blockIdx.x;
    const int c = bid & 31, hh = (bid >> 5) & 31, b = bid >> 10;
    const int tid = threadIdx.x;
    const int wv = tid >> 6, ln = tid & 63;
    const int r0 = b * LSEQ + c * CHUNK;
    const int s0 = c * CHUNK;

    // async-stage B^T
    {
        const int row16 = ln >> 2, col8 = (ln & 3) * 8;
        const __hip_bfloat16* Bb = BT + (size_t)b * DS * LSEQ + s0 + wv * 32 + col8;
        #pragma unroll
        for (int j = 0; j < 8; ++j)
            direct_load16(Bb + (size_t)(j * 16 + row16) * LSEQ, &lBT[wv][j * 512]);
    }

    // inclusive cumsum of la_s = A*dt_s (Hillis-Steele)
    float dt_s = 0.f;
    if (tid < CHUNK) {
        dt_s = dtv[(size_t)(r0 + tid) * NH + hh];
        sc[0][tid] = -__expf(A_log[hh]) * dt_s;
    }
    __syncthreads();
    int src = 0;
    for (int off = 1; off < CHUNK; off <<= 1) {
        if (tid < CHUNK)
            sc[src ^ 1][tid] = sc[src][tid] + ((tid >= off) ? sc[src][tid - off] : 0.f);
        __syncthreads();
        src ^= 1;
    }
    if (tid < CHUNK) {
        float Lc = sc[src][tid];
        lcg[(size_t)bid * CHUNK + tid] = Lc;
        lw[tid] = dt_s * __expf(sc[src][CHUNK - 1] - Lc);
    }
    __syncthreads();

    // stage weighted X^T
    {
        const int p = tid >> 2, ks = tid & 3;
        const __hip_bfloat16* xr = xT + (size_t)(b * DSSM + hh * HD + p) * LSEQ + s0 + ks * 32;
        #pragma unroll
        for (int v = 0; v < 4; ++v) {
            bf16x8 xv = *(const bf16x8*)&xr[v * 8];
            float4 w0 = *(const float4*)&lw[ks * 32 + v * 8];
            float4 w1 = *(const float4*)&lw[ks * 32 + v * 8 + 4];
            bf16x8 o;
            o[0] = to_bf((float)xv[0] * w0.x); o[1] = to_bf((float)xv[1] * w0.y);
            o[2] = to_bf((float)xv[2] * w0.z); o[3] = to_bf((float)xv[3] * w0.w);
            o[4] = to_bf((float)xv[4] * w1.x); o[5] = to_bf((float)xv[5] * w1.y);
            o[6] = to_bf((float)xv[6] * w1.z); o[7] = to_bf((float)xv[7] * w1.w);
            *(bf16x8*)&lXT[ks][p * 32 + v * 8] = o;
        }
    }
    __syncthreads();

    const int lane15 = ln & 15, quad = ln >> 4;
    f32x4 acc[4][2] = {};
    #pragma unroll
    for (int ks = 0; ks < 4; ++ks) {
        bf16x8 af[4], bf[2];
        #pragma unroll
        for (int mi = 0; mi < 4; ++mi)
            af[mi] = *(const bf16x8*)&lXT[ks][(mi * 16 + lane15) * 32 + quad * 8];
        #pragma unroll
        for (int ni = 0; ni < 2; ++ni)
            bf[ni] = *(const bf16x8*)&lBT[ks][(wv * 32 + ni * 16 + lane15) * 32 + quad * 8];
        #pragma unroll
        for (int mi = 0; mi < 4; ++mi)
            #pragma unroll
            for (int ni = 0; ni < 2; ++ni)
                acc[mi][ni] = __builtin_amdgcn_mfma_f32_16x16x32_bf16(af[mi], bf[ni], acc[mi][ni], 0, 0, 0);
    }

    __hip_bfloat16* sb = sst + (size_t)bid * (HD * DS);
    #pragma unroll
    for (int mi = 0; mi < 4; ++mi)
        #pragma unroll
        for (int ni = 0; ni < 2; ++ni) {
            int p0 = mi * 16 + quad * 4;
            int n0 = wv * 32 + ni * 16 + lane15;
            #pragma unroll
            for (int r = 0; r < 4; ++r)
                sb[(size_t)(p0 + r) * DS + n0] = __float2bfloat16(acc[mi][ni][r]);
        }
}

// ---------------- Phase B: inter-chunk prefix (in-place Sloc -> h_init) ----------------
// All 32 chunk loads are independent: batch into registers (one latency
// exposure), recurrence in regs, store all back.
__global__ __launch_bounds__(256) void chunk_scan(__hip_bfloat16* __restrict__ sst,
                                                  const float* __restrict__ lcg) {
    const int bid = blockIdx.x;               // 2048
    const int bh = bid >> 5;
    const int elem = (bid & 31) * 256 + threadIdx.x;
    size_t base = (size_t)bh * NCH * (HD * DS) + elem;
    const float* lg = lcg + (size_t)bh * NCH * CHUNK;

    float v[NCH];
    #pragma unroll
    for (int cc = 0; cc < NCH; ++cc)
        v[cc] = __bfloat162float(sst[base + (size_t)cc * (HD * DS)]);

    float h = 0.f;
    #pragma unroll
    for (int cc = 0; cc < NCH; ++cc) {
        float cq = __expf(lg[cc * CHUNK + CHUNK - 1]);
        float sv = v[cc];
        v[cc] = h;
        h = cq * h + sv;
    }

    #pragma unroll
    for (int cc = 0; cc < NCH; ++cc)
        sst[base + (size_t)cc * (HD * DS)] = __float2bfloat16(v[cc]);
}

// ---------------- Phase C: Y = (mask(C B^T)*dt) @ X + diag(cum) C @ h^T + D*x ----------------
// Gt = B @ C^T orientation: s in regs, t in lanes -> S written as b64 (4 consecutive s).
__global__ __launch_bounds__(256) void chunk_y(const __hip_bfloat16* __restrict__ xT,
                                               const __hip_bfloat16* __restrict__ Bv,
                                               const __hip_bfloat16* __restrict__ Cv,
                                               const float* __restrict__ dtv,
                                               const float* __restrict__ lcg,
                                               const __hip_bfloat16* __restrict__ sst,
                                               const float* __restrict__ Dv,
                                               __hip_bfloat16* __restrict__ y) {
    __shared__ __bf16 lC[4][128 * 32];   // C slices over n; later S slices over s
    __shared__ __bf16 lB[4][128 * 32];   // B slices over n; later X^T slices over s
    __shared__ float sLc[CHUNK];
    __shared__ float sdt[CHUNK];

    const int bid = blockIdx.x;
    const int c = bid & 31, hh = (bid >> 5) & 31, b = bid >> 10;
    const int tid = threadIdx.x;
    const int wv = tid >> 6, ln = tid & 63;
    const int lane15 = ln & 15, quad = ln >> 4;
    const int r0 = b * LSEQ + c * CHUNK;

    const __hip_bfloat16* Cb = Cv + (size_t)r0 * DS;
    const __hip_bfloat16* Bb = Bv + (size_t)r0 * DS;
    const __hip_bfloat16* Hb = sst + (size_t)bid * (HD * DS);

    {
        const int i3 = ln & 3, i4 = ln >> 2;
        #pragma unroll
        for (int j = 0; j < 8; ++j) {
            direct_load16(Cb + (size_t)(j * 16 + i4) * DS + wv * 32 + i3 * 8, &lC[wv][j * 512]);
            direct_load16(Bb + (size_t)(j * 16 + i4) * DS + wv * 32 + i3 * 8, &lB[wv][j * 512]);
        }
    }
    if (tid < CHUNK) {
        sLc[tid] = lcg[(size_t)bid * CHUNK + tid];
        sdt[tid] = dtv[(size_t)(r0 + tid) * NH + hh];
    }
    __syncthreads();

    const int wrow = (wv >> 1) * 64, wcol = (wv & 1) * 64;  // Gt quadrant (s rows, t cols)
    const int wr2 = wv * 32;                                 // Y rows
    f32x4 acc[4][4] = {};
    f32x4 accY[2][4] = {};

    // Gt = B @ C^T (K=n) and Y2 = C @ h^T (K=n, h B-frags direct from global)
    #pragma unroll
    for (int ks = 0; ks < 4; ++ks) {
        bf16x8 af[4], bfr[4], af2[2], bh[4];
        #pragma unroll
        for (int i = 0; i < 4; ++i) {
            af[i]  = *(const bf16x8*)&lB[ks][(wrow + i * 16 + lane15) * 32 + quad * 8];   // B rows s
            bfr[i] = *(const bf16x8*)&lC[ks][(wcol + i * 16 + lane15) * 32 + quad * 8];   // C rows t
        }
        #pragma unroll
        for (int mi = 0; mi < 2; ++mi)
            af2[mi] = *(const bf16x8*)&lC[ks][(wr2 + mi * 16 + lane15) * 32 + quad * 8];
        #pragma unroll
        for (int ni = 0; ni < 4; ++ni)
            bh[ni] = *(const bf16x8*)&Hb[(size_t)(ni * 16 + lane15) * DS + ks * 32 + quad * 8];
        #pragma unroll
        for (int mi = 0; mi < 4; ++mi)
            #pragma unroll
            for (int ni = 0; ni < 4; ++ni)
                acc[mi][ni] = __builtin_amdgcn_mfma_f32_16x16x32_bf16(af[mi], bfr[ni], acc[mi][ni], 0, 0, 0);
        #pragma unroll
        for (int mi = 0; mi < 2; ++mi)
            #pragma unroll
            for (int ni = 0; ni < 4; ++ni)
                accY[mi][ni] = __builtin_amdgcn_mfma_f32_16x16x32_bf16(af2[mi], bh[ni], accY[mi][ni], 0, 0, 0);
    }

    // scale Y2 rows by cum_t = exp(Lc_t)
    #pragma unroll
    for (int mi = 0; mi < 2; ++mi)
        #pragma unroll
        for (int r = 0; r < 4; ++r) {
            float cum = __expf(sLc[wr2 + mi * 16 + quad * 4 + r]);
            #pragma unroll
            for (int ni = 0; ni < 4; ++ni) accY[mi][ni][r] *= cum;
        }

    __syncthreads();   // all Gt/Y2 LDS reads done

    // async-stage X^T from xT into lB (overlaps with S-mask VALU below)
    {
        const int row16 = ln >> 2, col8 = (ln & 3) * 8;
        const __hip_bfloat16* xr = xT + (size_t)(b * DSSM + hh * HD) * LSEQ + c * CHUNK + wv * 32 + col8;
        #pragma unroll
        for (int j = 0; j < 4; ++j)
            direct_load16(xr + (size_t)(j * 16 + row16) * LSEQ, &lB[wv][j * 512]);
    }

    // mask+decay Gt -> S[t][s], b64 writes (4 consecutive s per reg group)
    #pragma unroll
    for (int mi = 0; mi < 4; ++mi) {
        const int sb = wrow + mi * 16 + quad * 4;
        float el[4], dt4[4];
        #pragma unroll
        for (int r = 0; r < 4; ++r) { el[r] = sLc[sb + r]; dt4[r] = sdt[sb + r]; }
        #pragma unroll
        for (int ni = 0; ni < 4; ++ni) {
            const int t = wcol + ni * 16 + lane15;
            const float Lct = sLc[t];
            bf16x4v o;
            #pragma unroll
            for (int r = 0; r < 4; ++r) {
                const int s = sb + r;
                float v = (s <= t) ? acc[mi][ni][r] * __expf(Lct - el[r]) * dt4[r] : 0.f;
                o[r] = to_bf(v);
            }
            *(bf16x4v*)&lC[sb >> 5][t * 32 + (sb & 31)] = o;
        }
    }
    __syncthreads();

    // Y1 = S @ X (K=s)
    #pragma unroll
    for (int ks = 0; ks < 4; ++ks) {
        bf16x8 af2[2], bx[4];
        #pragma unroll
        for (int mi = 0; mi < 2; ++mi)
            af2[mi] = *(const bf16x8*)&lC[ks][(wr2 + mi * 16 + lane15) * 32 + quad * 8];
        #pragma unroll
        for (int ni = 0; ni < 4; ++ni)
            bx[ni] = *(const bf16x8*)&lB[ks][(ni * 16 + lane15) * 32 + quad * 8];
        #pragma unroll
        for (int mi = 0; mi < 2; ++mi)
            #pragma unroll
            for (int ni = 0; ni < 4; ++ni)
                accY[mi][ni] = __builtin_amdgcn_mfma_f32_16x16x32_bf16(af2[mi], bx[ni], accY[mi][ni], 0, 0, 0);
    }

    // + D * x  (x[t][p] still in lB)
    const float dsc = Dv[hh];
    #pragma unroll
    for (int mi = 0; mi < 2; ++mi)
        #pragma unroll
        for (int ni = 0; ni < 4; ++ni) {
            const int p0 = ni * 16 + lane15;
            #pragma unroll
            for (int r = 0; r < 4; ++r) {
                const int t = wr2 + mi * 16 + quad * 4 + r;
                accY[mi][ni][r] += dsc * (float)lB[t >> 5][p0 * 32 + (t & 31)];
            }
        }

    // epilogue
    __hip_bfloat16* yb = y + (size_t)r0 * DSSM + hh * HD;
    #pragma unroll
    for (int mi = 0; mi < 2; ++mi)
        #pragma unroll
        for (int ni = 0; ni < 4; ++ni) {
            const int p0 = ni * 16 + lane15;
            #pragma unroll
            for (int r = 0; r < 4; ++r) {
                const int t = wr2 + mi * 16 + quad * 4 + r;
                yb[(size_t)t * DSSM + p0] = __float2bfloat16(accY[mi][ni][r]);
            }
        }
}

// ---------------- y(+Dx already), gate, RMSNorm -> g (into zx cols [2048,4096)) ----------------
__global__ __launch_bounds__(256) void gnorm_kernel(const __hip_bfloat16* __restrict__ y,
                                                    __hip_bfloat16* __restrict__ zx,
                                                    const float* __restrict__ nw) {
    const int r = blockIdx.x;
    const int tid = threadIdx.x;
    const int c = tid * 8;
    const size_t off = (size_t)r * DSSM + c;
    bf16x8 yv8 = *(const bf16x8*)&y[off];
    bf16x8 zv8 = *(const bf16x8*)&zx[(size_t)r * NPAD + c];
    float gv[8];
    float ss = 0.f;
    #pragma unroll
    for (int i = 0; i < 8; ++i) {
        float yv = (float)yv8[i];
        float z = (float)zv8[i];
        float gq = yv * (z / (1.f + __expf(-z)));
        gv[i] = gq;
        ss += gq * gq;
    }
    #pragma unroll
    for (int o = 32; o; o >>= 1) ss += __shfl_xor(ss, o, 64);
    __shared__ float ws4[4];
    if ((tid & 63) == 0) ws4[tid >> 6] = ss;
    __syncthreads();
    const float tot = ws4[0] + ws4[1] + ws4[2] + ws4[3];
    const float scale = rsqrtf(tot * (1.f / (float)DSSM) + 1e-5f);
    bf16x8 o;
    #pragma unroll
    for (int i = 0; i < 8; ++i) o[i] = to_bf(gv[i] * scale * nw[c + i]);
    *(bf16x8*)&zx[(size_t)r * NPAD + DSSM + c] = o;
}

// ---------------- launch ----------------
extern "C" void kernel_launch(void* const* d_in, const int* in_sizes, int n_in,
                              void* d_out, int out_size, void* d_ws, size_t ws_size,
                              hipStream_t stream) {
    const float* u       = (const float*)d_in[0];
    const float* W_in    = (const float*)d_in[1];
    const float* conv_w  = (const float*)d_in[2];
    const float* conv_b  = (const float*)d_in[3];
    const float* dt_bias = (const float*)d_in[4];
    const float* A_log   = (const float*)d_in[5];
    const float* Dv      = (const float*)d_in[6];
    const float* norm_w  = (const float*)d_in[7];
    const float* W_out   = (const float*)d_in[8];
    float* out = (float*)d_out;

    char* ws = (char*)d_ws;
    size_t off = 0;
    auto alloc = [&](size_t bytes) { char* p = ws + off; off += (bytes + 255) & ~(size_t)255; return p; };

    // ~210 MB total
    __hip_bfloat16* ub    = (__hip_bfloat16*)alloc((size_t)ROWS * DM * 2);       // 16.8 MB
    __hip_bfloat16* winb  = (__hip_bfloat16*)alloc((size_t)NPAD * DM * 2);       //  9.2 MB
    __hip_bfloat16* woutb = (__hip_bfloat16*)alloc((size_t)DM * DSSM * 2);       //  4.2 MB
    __hip_bfloat16* zx    = (__hip_bfloat16*)alloc((size_t)ROWS * NPAD * 2);     // 73.4 MB
    __hip_bfloat16* yb    = (__hip_bfloat16*)alloc((size_t)ROWS * DSSM * 2);     // 33.6 MB
    __hip_bfloat16* sst   = (__hip_bfloat16*)alloc((size_t)NBHC * HD * DS * 2);  // 33.6 MB
    __hip_bfloat16* xT    = (__hip_bfloat16*)alloc((size_t)ROWS * DSSM * 2);     // 33.6 MB
    __hip_bfloat16* BT    = (__hip_bfloat16*)alloc((size_t)ROWS * DS * 2);       //  2.1 MB

    // ub dead after GEMM1 -> B/C (bf16) + dt (fp32)
    __hip_bfloat16* Bvp = (__hip_bfloat16*)ub;
    __hip_bfloat16* Cvp = Bvp + (size_t)ROWS * DS;
    float*          dtv = (float*)(Cvp + (size_t)ROWS * DS);
    // winb dead after GEMM1 -> Lc cumsums
    float*          lcg = (float*)winb;

    // merged converts
    convert_all<<<(unsigned)((N1 + N2 + N3) / 4 / 256), 256, 0, stream>>>(
        u, W_in, W_out, ub, winb, woutb);

    // GEMM1: zx[8192, 4480](bf16) = u @ W_in^T (padded), 1D swizzled grid
    gemm_bt<__hip_bfloat16><<<(ROWS / 128) * (NPAD / 128), 256, 0, stream>>>(
        ub, winb, zx, ROWS, NPAD, DM, DM, NPAD);

    // fused conv + silu + dt + transposes (overwrites ub-region with B/C/dt)
    conv_fused<<<dim3(37, ROWS / 64), 256, 0, stream>>>(
        zx, conv_w, conv_b, dt_bias, xT, Bvp, Cvp, BT, dtv);

    // chunked scan: local states -> prefix -> Y
    chunk_local<<<NBHC, 256, 0, stream>>>(xT, BT, dtv, A_log, sst, lcg);
    chunk_scan<<<NBHC, 256, 0, stream>>>(sst, lcg);
    chunk_y<<<NBHC, 256, 0, stream>>>(xT, Bvp, Cvp, dtv, lcg, sst, Dv, yb);

    // gate + norm; writes g into zx cols [2048, 4096)
    gnorm_kernel<<<ROWS, 256, 0, stream>>>(yb, zx, norm_w);

    // GEMM2: out[8192,1024](fp32) = g @ W_out^T   (g lives in zx, lda = NPAD)
    gemm_bt<float><<<(ROWS / 128) * (DM / 128), 256, 0, stream>>>(
        zx + DSSM, woutb, out, ROWS, DM, DSSM, NPAD, DM);
}